// Round 1
// baseline (3796.305 us; speedup 1.0000x reference)
//
#include <hip/hip_runtime.h>
#include <hip/hip_bf16.h>

// Problem constants (B,C,H,G) = (4,128,8,64); F=4096, DH=16, NR=2G-1=127 rings.
#define Bn 4
#define Cn 128
#define Hn 8
#define DHn 16
#define Fn 4096
#define NRINGS 127
#define RW 64        // max ring width
#define NS 16        // key slices per (b,h)
#define KSL 256      // keys per slice (NS*KSL = F)

// ---------------------------------------------------------------------------
// Kernel 0: Q0 = Wq0@x, K = Wk0@x, V = Wv0@x, feats = x
// grid = B * (F/64) = 256 WGs, 256 threads
// ---------------------------------------------------------------------------
__global__ __launch_bounds__(256) void qkvInit(
    const float* __restrict__ x, const float* __restrict__ Wq0,
    const float* __restrict__ Wk0, const float* __restrict__ Wv0,
    float* __restrict__ Q0, float* __restrict__ Kg, float* __restrict__ Vg,
    float* __restrict__ feats)
{
    int b  = blockIdx.x >> 6;
    int n0 = (blockIdx.x & 63) << 6;
    __shared__ float xs[128][64];
    int t = threadIdx.x;
    for (int idx = t; idx < 8192; idx += 256) {
        int c = idx >> 6, nn = idx & 63;
        float v = x[((b*Cn + c) << 12) + n0 + nn];
        xs[c][nn] = v;
        feats[((b*Cn + c) << 12) + n0 + nn] = v;
    }
    __syncthreads();
    for (int idx = t; idx < 8192; idx += 256) {
        int o = idx >> 6, nn = idx & 63;
        float aq = 0.f, ak = 0.f, av = 0.f;
        for (int c = 0; c < 128; ++c) {
            float xv = xs[c][nn];
            aq += Wq0[o*128 + c] * xv;
            ak += Wk0[o*128 + c] * xv;
            av += Wv0[o*128 + c] * xv;
        }
        int gi = ((b*Cn + o) << 12) + n0 + nn;
        Q0[gi] = aq; Kg[gi] = ak; Vg[gi] = av;
    }
}

// ---------------------------------------------------------------------------
// Kernel A: flash-attention partials for ring r.
// grid = B*H*NS = 512 WGs, 256 threads. WG (b,h,s) handles keys
// [s*KSL, (s+1)*KSL) for all ring queries; online softmax; writes (m,l,o16).
// Thread layout: 32 query-pairs x 8 key-parts. Each thread: 2 queries, 32 keys.
// ---------------------------------------------------------------------------
__global__ __launch_bounds__(256) void flashA(
    const float* __restrict__ Q0, const float* __restrict__ Kg,
    const float* __restrict__ Vg, const int* __restrict__ rings,
    const int* __restrict__ rsz, float* __restrict__ pm,
    float* __restrict__ pl, float* __restrict__ po, int r)
{
    int wg = blockIdx.x;
    int s = wg & (NS - 1);
    int h = (wg >> 4) & 7;
    int b = wg >> 7;
    int n = rsz[r];
    int t = threadIdx.x;

    __shared__ float Ks[KSL][16];
    __shared__ float Vs[KSL][16];
    __shared__ float qs[RW][17];
    __shared__ int   cols[RW];

    if (t < RW) cols[t] = (t < n) ? rings[r*RW + t] : 0;

    // stage K/V slice, key-major (t == key index within slice)
    {
        int kbase = ((b*Cn + h*DHn) << 12) + s*KSL + t;
        float kc[16], vc[16];
#pragma unroll
        for (int d = 0; d < 16; ++d) {
            kc[d] = Kg[kbase + (d << 12)];
            vc[d] = Vg[kbase + (d << 12)];
        }
#pragma unroll
        for (int d4 = 0; d4 < 4; ++d4) {
            *(float4*)&Ks[t][d4*4] = make_float4(kc[d4*4], kc[d4*4+1], kc[d4*4+2], kc[d4*4+3]);
            *(float4*)&Vs[t][d4*4] = make_float4(vc[d4*4], vc[d4*4+1], vc[d4*4+2], vc[d4*4+3]);
        }
    }
    __syncthreads();
    // stage ring queries (need cols)
    for (int idx = t; idx < n*16; idx += 256) {
        int q = idx >> 4, d = idx & 15;
        qs[q][d] = Q0[((b*Cn + h*DHn + d) << 12) + cols[q]];
    }
    __syncthreads();

    int qg   = t >> 3;          // 0..31
    int part = t & 7;           // 0..7
    int qa = 2*qg, qb = 2*qg + 1;
    bool actA = (qa < n), actB = (qb < n);

    float qv0[16], qv1[16];
#pragma unroll
    for (int d = 0; d < 16; ++d) {
        qv0[d] = actA ? qs[qa][d] : 0.f;
        qv1[d] = actB ? qs[qb][d] : 0.f;
    }

    float m0 = -1e30f, l0 = 0.f, m1 = -1e30f, l1 = 0.f;
    float o0[16], o1[16];
#pragma unroll
    for (int d = 0; d < 16; ++d) { o0[d] = 0.f; o1[d] = 0.f; }

#pragma unroll 2
    for (int i = 0; i < KSL/8; ++i) {
        int kk = i*8 + part;
        float kc[16], vc[16];
        *(float4*)&kc[0]  = *(const float4*)&Ks[kk][0];
        *(float4*)&kc[4]  = *(const float4*)&Ks[kk][4];
        *(float4*)&kc[8]  = *(const float4*)&Ks[kk][8];
        *(float4*)&kc[12] = *(const float4*)&Ks[kk][12];
        float sc0 = 0.f, sc1 = 0.f;
#pragma unroll
        for (int d = 0; d < 16; ++d) { sc0 += qv0[d]*kc[d]; sc1 += qv1[d]*kc[d]; }
        sc0 *= 0.25f; sc1 *= 0.25f;

        *(float4*)&vc[0]  = *(const float4*)&Vs[kk][0];
        *(float4*)&vc[4]  = *(const float4*)&Vs[kk][4];
        *(float4*)&vc[8]  = *(const float4*)&Vs[kk][8];
        *(float4*)&vc[12] = *(const float4*)&Vs[kk][12];

        float mn0 = fmaxf(m0, sc0);
        float cr0 = __expf(m0 - mn0);
        float p0  = __expf(sc0 - mn0);
        m0 = mn0; l0 = l0*cr0 + p0;
        float mn1 = fmaxf(m1, sc1);
        float cr1 = __expf(m1 - mn1);
        float p1  = __expf(sc1 - mn1);
        m1 = mn1; l1 = l1*cr1 + p1;
#pragma unroll
        for (int d = 0; d < 16; ++d) {
            o0[d] = o0[d]*cr0 + p0*vc[d];
            o1[d] = o1[d]*cr1 + p1*vc[d];
        }
    }

    // reduce across the 8 key-parts (lanes t^1, t^2, t^4 within wave)
#pragma unroll
    for (int mask = 1; mask < 8; mask <<= 1) {
        float mo = __shfl_xor(m0, mask);
        float lo = __shfl_xor(l0, mask);
        float mn = fmaxf(m0, mo);
        float c0 = __expf(m0 - mn), c1 = __expf(mo - mn);
        l0 = l0*c0 + lo*c1;
#pragma unroll
        for (int d = 0; d < 16; ++d) {
            float oo = __shfl_xor(o0[d], mask);
            o0[d] = o0[d]*c0 + oo*c1;
        }
        m0 = mn;

        float mo1 = __shfl_xor(m1, mask);
        float lo1 = __shfl_xor(l1, mask);
        float mn1 = fmaxf(m1, mo1);
        float d0 = __expf(m1 - mn1), d1 = __expf(mo1 - mn1);
        l1 = l1*d0 + lo1*d1;
#pragma unroll
        for (int d = 0; d < 16; ++d) {
            float oo = __shfl_xor(o1[d], mask);
            o1[d] = o1[d]*d0 + oo*d1;
        }
        m1 = mn1;
    }

    if (part == 0) {
        int pb = ((b*Hn + h)*NS + s)*RW;
        if (actA) {
            pm[pb + qa] = m0; pl[pb + qa] = l0;
#pragma unroll
            for (int d = 0; d < 16; ++d) po[(pb + qa)*16 + d] = o0[d];
        }
        if (actB) {
            pm[pb + qb] = m1; pl[pb + qb] = l1;
#pragma unroll
            for (int d = 0; d < 16; ++d) po[(pb + qb)*16 + d] = o1[d];
        }
    }
}

// ---------------------------------------------------------------------------
// Kernel B: combine slice partials for ring column j, write feats, update K/V.
// grid = B*RW = 256 WGs, 128 threads (thread i = channel; h=i>>4, d=i&15).
// ---------------------------------------------------------------------------
__global__ __launch_bounds__(128) void combineB(
    const float* __restrict__ pm, const float* __restrict__ pl,
    const float* __restrict__ po, const float* __restrict__ Wk0,
    const float* __restrict__ Wv0, const int* __restrict__ rings,
    const int* __restrict__ rsz, float* __restrict__ feats,
    float* __restrict__ Kg, float* __restrict__ Vg, int r)
{
    int j = blockIdx.x & 63;
    int b = blockIdx.x >> 6;
    int n = rsz[r];
    __shared__ float outc[128];
    int i = threadIdx.x;
    int col = 0;
    if (j < n) {
        col = rings[r*RW + j];
        int h = i >> 4, d = i & 15;
        int base = ((b*Hn + h)*NS)*RW + j;   // s stride = RW
        float mstar = -1e30f;
        for (int s = 0; s < NS; ++s) mstar = fmaxf(mstar, pm[base + s*RW]);
        float lstar = 0.f, osum = 0.f;
        for (int s = 0; s < NS; ++s) {
            float e = __expf(pm[base + s*RW] - mstar);
            lstar += pl[base + s*RW] * e;
            osum  += po[(base + s*RW)*16 + d] * e;
        }
        float outv = osum / lstar + feats[((b*Cn + i) << 12) + col];
        outc[i] = outv;
        feats[((b*Cn + i) << 12) + col] = outv;
    }
    __syncthreads();
    if (j < n) {
        float ka = 0.f, va = 0.f;
        for (int c = 0; c < 128; ++c) {
            float xv = outc[c];
            ka += Wk0[i*128 + c] * xv;
            va += Wv0[i*128 + c] * xv;
        }
        Kg[((b*Cn + i) << 12) + col] = ka;
        Vg[((b*Cn + i) << 12) + col] = va;
    }
}

// ---------------------------------------------------------------------------
// Epilogue 1: anchor-derived vectors. Va = Wv0@anchor, Kn = normalize(Wk1@anchor)
// grid = B, 128 threads.
// ---------------------------------------------------------------------------
__global__ __launch_bounds__(128) void epi1(
    const float* __restrict__ feats, const float* __restrict__ Wv0,
    const float* __restrict__ Wk1, const int* __restrict__ rings,
    float* __restrict__ Va, float* __restrict__ Kn)
{
    int b = blockIdx.x;
    int i = threadIdx.x;
    int anchor = rings[0];
    __shared__ float la[128];
    __shared__ float kk2[128];
    la[i] = feats[((b*Cn + i) << 12) + anchor];
    __syncthreads();
    float va = 0.f, k1 = 0.f;
    for (int c = 0; c < 128; ++c) {
        va += Wv0[i*128 + c] * la[c];
        k1 += Wk1[i*128 + c] * la[c];
    }
    Va[b*128 + i] = va;
    kk2[i] = k1*k1;
    __syncthreads();
    float ss = 0.f;
    int hb = i & ~15;
    for (int d = 0; d < 16; ++d) ss += kk2[hb + d];
    Kn[b*128 + i] = k1 * rsqrtf(ss + 1e-8f);
}

// ---------------------------------------------------------------------------
// Epilogue 2: per (b,col): q1 = Wq1@(x_col + Va); normalize per head; cosine
// with Kn; final = 0.5 + sum_i(qn_i*kn_i)/16. grid = B*F, 128 threads.
// ---------------------------------------------------------------------------
__global__ __launch_bounds__(128) void epi2(
    const float* __restrict__ x, const float* __restrict__ Wq1,
    const float* __restrict__ Va, const float* __restrict__ Kn,
    float* __restrict__ scores)
{
    int col = blockIdx.x & (Fn - 1);
    int b   = blockIdx.x >> 12;
    int i = threadIdx.x;
    __shared__ float lx[128];
    __shared__ float q2[128];
    __shared__ float mp[128];
    lx[i] = x[((b*Cn + i) << 12) + col] + Va[b*128 + i];
    __syncthreads();
    float q1 = 0.f;
    for (int c = 0; c < 128; ++c) q1 += Wq1[i*128 + c] * lx[c];
    q2[i] = q1*q1;
    __syncthreads();
    float ss = 0.f;
    int hb = i & ~15;
    for (int d = 0; d < 16; ++d) ss += q2[hb + d];
    float qn = q1 * rsqrtf(ss + 1e-8f);
    mp[i] = qn * Kn[b*128 + i];
    __syncthreads();
    for (int st = 64; st > 0; st >>= 1) {
        if (i < st) mp[i] += mp[i + st];
        __syncthreads();
    }
    if (i == 0) scores[(b << 12) + col] = 0.5f + mp[0] * (1.0f/16.0f);
}

// ---------------------------------------------------------------------------
// Launcher. Workspace layout (floats):
//   Q0: 2097152 | Kg: 2097152 | Vg: 2097152 | pm: 32768 | pl: 32768
//   po: 524288 | Va: 512 | Kn: 512   -> total 6,882,304 floats (~27.5 MB)
// ---------------------------------------------------------------------------
extern "C" void kernel_launch(void* const* d_in, const int* in_sizes, int n_in,
                              void* d_out, int out_size, void* d_ws, size_t ws_size,
                              hipStream_t stream) {
    const float* x   = (const float*)d_in[0];
    const float* Wq0 = (const float*)d_in[1];
    const float* Wk0 = (const float*)d_in[2];
    const float* Wv0 = (const float*)d_in[3];
    const float* Wq1 = (const float*)d_in[4];
    const float* Wk1 = (const float*)d_in[5];
    const int*   rings = (const int*)d_in[6];
    const int*   rsz   = (const int*)d_in[7];

    float* feats  = (float*)d_out;                 // (B,C,F)
    float* scores = feats + Bn*Cn*Fn;              // (B,F)

    float* ws = (float*)d_ws;
    float* Q0 = ws;
    float* Kg = ws + 2097152;
    float* Vg = ws + 4194304;
    float* pm = ws + 6291456;
    float* pl = pm + 32768;
    float* po = pl + 32768;
    float* Va = po + 524288;
    float* Kn = Va + 512;

    qkvInit<<<256, 256, 0, stream>>>(x, Wq0, Wk0, Wv0, Q0, Kg, Vg, feats);

    for (int r = 0; r < NRINGS; ++r) {
        flashA<<<Bn*Hn*NS, 256, 0, stream>>>(Q0, Kg, Vg, rings, rsz, pm, pl, po, r);
        combineB<<<Bn*RW, 128, 0, stream>>>(pm, pl, po, Wk0, Wv0, rings, rsz,
                                            feats, Kg, Vg, r);
    }

    epi1<<<Bn, 128, 0, stream>>>(feats, Wv0, Wk1, rings, Va, Kn);
    epi2<<<Bn*Fn, 128, 0, stream>>>(x, Wq1, Va, Kn, scores);
}